// Round 10
// baseline (4063.086 us; speedup 1.0000x reference)
//
#include <hip/hip_runtime.h>

namespace {

typedef _Float16 __attribute__((ext_vector_type(2))) h2v;   // one VGPR = 2 f16

constexpr int KSTEPS = 1024;
constexpr int BTOT   = 512;
constexpr size_t OFF_R = (size_t)BTOT * KSTEPS * 5;                      // rates offset
constexpr size_t OFF_D = OFF_R + (size_t)BTOT * KSTEPS * 8;              // dhid offset

__device__ __forceinline__ float sigf(float x) {
    return 1.0f / (1.0f + __expf(-x));
}
__device__ __forceinline__ float tanhfast(float x) {
    float e2 = __expf(2.0f * x);
    return 1.0f - 2.0f / (e2 + 1.0f);   // inf-safe
}
__device__ __forceinline__ float fdot2(h2v a, h2v b, float c) {
    return __builtin_amdgcn_fdot2(a, b, c, false);   // v_dot2_f32_f16
}

// RHS of the 5-state chain (flux form, matches reference exactly)
#define CHAIN_RHS(d, yy)                                   \
    {                                                      \
        float f1 = kf1 * yy[0] - kr1 * yy[1];              \
        float f2 = kf2 * yy[1] - kr2 * yy[2];              \
        float f3 = kf3 * yy[2] - kr3 * yy[3];              \
        float f4 = kf4 * yy[3] - kr4 * yy[4];              \
        d[0] = -f1;                                        \
        d[1] = f1 - f2;                                    \
        d[2] = f2 - f3;                                    \
        d[3] = f3 - f4;                                    \
        d[4] = f4;                                         \
    }

// Register-budget law (r1-r6): budget = 256 / ceil(waves_per_WG / 4).
// 768-thread WG -> 84 VGPRs. f16-packed hi weights (48 regs) + fdot2 fit.
// Accuracy model (r2/r3/v9 evidence): gate-error flip threshold ~0.02-0.05.
//   - v9 failed (160): missing Wih_lo*x term with x up to O(1e3) -> ~0.02-0.3.
//   - fix: Wih f16-residuals in LDS, third fdot2 term -> all error terms <=1e-4.
//   - W_hh-hi-only (gh err ~5e-5) and h-as-f16 (~7e-5) are far below threshold.
__global__ __launch_bounds__(768, 3) void rnn_v10(
    const float* __restrict__ y0,     const float* __restrict__ u_seq,
    const float* __restrict__ dt_seq, const float* __restrict__ W_lift,
    const float* __restrict__ b_lift, const float* __restrict__ W_ih,
    const float* __restrict__ W_hh,   const float* __restrict__ b_ih,
    const float* __restrict__ b_hh,   const float* __restrict__ W_head,
    const float* __restrict__ b_head, const float* __restrict__ u2y,
    float* __restrict__ out)
{
    const int t  = threadIdx.x;          // 0..767
    const int hf = (t >= 384) ? 1 : 0;   // column half (wave-uniform)
    const int o  = t - hf * 384;         // owned GRU output row 0..383
    const int wg = blockIdx.x;
    const int b0 = wg * 2;               // two batch rows per WG

    __shared__ alignas(16) float sWlift[64 * 9];
    __shared__ float sblift[64];
    __shared__ alignas(16) float sWheadP[13 * 132];   // padded stride 132
    __shared__ float sbhead[16];
    __shared__ float sU2Y[20];                        // (U=4, P=5) row-major
    __shared__ alignas(16) _Float16 sX2hi[2][64];     // x high f16
    __shared__ alignas(16) _Float16 sX2lo[2][64];     // x residual f16
    __shared__ alignas(16) _Float16 sWihLo[2][384][36];  // W_ih f16 residuals
                                                         // (72B row stride: b64-aligned, ~2-way banks)
    __shared__ alignas(16) float sH[2][128];          // h fp32 (head consumer)
    __shared__ alignas(16) _Float16 sH2[2][128];      // h as f16 (gh consumer)
    __shared__ alignas(16) float sGiP[2][2][384];     // [half][row][out]
    __shared__ alignas(16) float sGhP[2][2][384];
    __shared__ float sY[2][8];
    __shared__ float sRates[2][8];
    __shared__ float sDhid[2][8];
    __shared__ alignas(16) float sU[2][2][4];         // [buf][row][4]
    __shared__ float sDt[2][2];

    // ---- per-thread half weight rows, f16-packed hi: 48 VGPRs ----
    h2v wih2[16];   // W_ih[o][hf*32 .. +31] (hi)
    h2v whh2[32];   // W_hh[o][hf*64 .. +63] (hi)
    {
        const float* p = W_ih + (size_t)o * 64 + hf * 32;
#pragma unroll
        for (int i = 0; i < 16; i++)
            wih2[i] = h2v{(_Float16)p[2 * i], (_Float16)p[2 * i + 1]};
        const float* q = W_hh + (size_t)o * 128 + hf * 64;
#pragma unroll
        for (int i = 0; i < 32; i++)
            whh2[i] = h2v{(_Float16)q[2 * i], (_Float16)q[2 * i + 1]};
    }
    const float bihv = hf ? 0.0f : b_ih[o];
    const float bhhv = hf ? 0.0f : b_hh[o];

    // pin packed hi weights (48 regs fit the 84 budget -> no spill possible)
#pragma unroll
    for (int i = 0; i < 16; i++) asm volatile("" : "+v"(wih2[i]));
#pragma unroll
    for (int i = 0; i < 32; i++) asm volatile("" : "+v"(whh2[i]));

    // ---- cooperative LDS init ----
    for (int i = t; i < 576; i += 768) sWlift[i] = W_lift[i];
    if (t < 64) sblift[t] = b_lift[t];
    for (int i = t; i < 13 * 128; i += 768) {
        int oo = i >> 7, c = i & 127;
        sWheadP[oo * 132 + c] = W_head[i];
    }
    // W_ih f16 residuals -> LDS
    for (int i = t; i < 2 * 384 * 32; i += 768) {
        int hh = i / (384 * 32);
        int rem = i - hh * 384 * 32;
        int oo = rem >> 5, c = rem & 31;
        float w = W_ih[(size_t)oo * 64 + hh * 32 + c];
        _Float16 wh = (_Float16)w;
        sWihLo[hh][oo][c] = (_Float16)(w - (float)wh);
    }
    if (t < 13) sbhead[t] = b_head[t];
    if (t < 20) sU2Y[t] = u2y[t];
    if (t < 256) {
        sH[t >> 7][t & 127] = 0.0f;
        sH2[t >> 7][t & 127] = (_Float16)0.0f;
    }
    if (t < 10) { int r = t / 5, s = t % 5; sY[r][s] = y0[(b0 + r) * 5 + s] + 0.01f; }
    // gh(k=0) partials: h0 = 0 -> gh = b_hh (half 0 carries the bias)
    sGhP[hf][0][o] = bhhv;
    sGhP[hf][1][o] = bhhv;
    if (t < 8)  { int r = t >> 2, m = t & 3; sU[0][r][m] = u_seq[((size_t)(b0 + r) * KSTEPS + 0) * 4 + m]; }
    if (t >= 8 && t < 10) { int r = t - 8; sDt[0][r] = dt_seq[(size_t)(b0 + r) * KSTEPS + 0]; }
    __syncthreads();

    float4 upf = make_float4(0.f, 0.f, 0.f, 0.f);  // u prefetch (lanes 256,257)
    float  dpf = 0.f;                              // dt prefetch (lanes 258,259)

    for (int k = 0; k < KSTEPS; k++) {
        // ---------- phase A: prefetch issue + lift ----------
        if (t >= 256 && t < 260 && (k + 1) < KSTEPS) {
            if (t < 258) {
                int r = t - 256;
                upf = *(const float4*)&u_seq[((size_t)(b0 + r) * KSTEPS + (k + 1)) * 4];
            } else {
                int r = t - 258;
                dpf = dt_seq[(size_t)(b0 + r) * KSTEPS + (k + 1)];
            }
        }
        if (t < 128) {
            int r = t >> 6, l = t & 63;
            const float* wl = &sWlift[l * 9];
            float acc = sblift[l];
            acc = fmaf(wl[0], sU[k & 1][r][0], acc);
            acc = fmaf(wl[1], sU[k & 1][r][1], acc);
            acc = fmaf(wl[2], sU[k & 1][r][2], acc);
            acc = fmaf(wl[3], sU[k & 1][r][3], acc);
            acc = fmaf(wl[4], sY[r][0], acc);
            acc = fmaf(wl[5], sY[r][1], acc);
            acc = fmaf(wl[6], sY[r][2], acc);
            acc = fmaf(wl[7], sY[r][3], acc);
            acc = fmaf(wl[8], sY[r][4], acc);
            float xf = acc * sigf(acc);             // silu, fp32
            _Float16 xh = (_Float16)xf;
            sX2hi[r][l] = xh;
            sX2lo[r][l] = (_Float16)(xf - (float)xh);   // residual
        }
        __syncthreads();

        // ---------- phase B: gi = Whi*xhi + Whi*xlo + Wlo*xhi ----------
        {
            float g0 = bihv, g1 = 0.0f;
            const h2v* xh0 = (const h2v*)&sX2hi[0][hf * 32];
            const h2v* xh1 = (const h2v*)&sX2hi[1][hf * 32];
            const h2v* xl0 = (const h2v*)&sX2lo[0][hf * 32];
            const h2v* xl1 = (const h2v*)&sX2lo[1][hf * 32];
            const h2v* wlo = (const h2v*)&sWihLo[hf][o][0];
#pragma unroll
            for (int i = 0; i < 16; i++) {
                h2v wl = wlo[i];
                g0 = fdot2(wih2[i], xh0[i], g0);
                g0 = fdot2(wih2[i], xl0[i], g0);
                g0 = fdot2(wl, xh0[i], g0);
                g1 = fdot2(wih2[i], xh1[i], g1);
                g1 = fdot2(wih2[i], xl1[i], g1);
                g1 = fdot2(wl, xh1[i], g1);
            }
            sGiP[hf][0][o] = g0;
            sGiP[hf][1][o] = g1;
        }
        __syncthreads();

        // ---------- phase C: GRU gates -> h_new ----------
        if (t < 256) {
            int r = t >> 7, q = t & 127;
            float ir  = sGiP[0][r][q]       + sGiP[1][r][q];
            float iz  = sGiP[0][r][q + 128] + sGiP[1][r][q + 128];
            float in_ = sGiP[0][r][q + 256] + sGiP[1][r][q + 256];
            float hr  = sGhP[0][r][q]       + sGhP[1][r][q];
            float hz  = sGhP[0][r][q + 128] + sGhP[1][r][q + 128];
            float hn  = sGhP[0][r][q + 256] + sGhP[1][r][q + 256];
            float rr = sigf(ir + hr);
            float z  = sigf(iz + hz);
            float n  = tanhfast(fmaf(rr, hn, in_));
            float h  = sH[r][q];
            float hnew = fmaf(z, h - n, n);     // (1-z)*n + z*h
            sH[r][q] = hnew;
            sH2[r][q] = (_Float16)hnew;
        }
        __syncthreads();

        // ---------- phase D: head, 8 lanes per output (fp32) ----------
        if (t < 208) {
            int og = t >> 3, sub = t & 7;           // output group 0..25, sub-lane 0..7
            int r  = (og >= 13) ? 1 : 0;
            int oo = og - 13 * r;
            const float4* wv = (const float4*)(&sWheadP[oo * 132 + sub * 16]);
            const float4* hv = (const float4*)(&sH[r][sub * 16]);
            float4 w0 = wv[0], w1 = wv[1], w2 = wv[2], w3 = wv[3];
            float4 h0 = hv[0], h1 = hv[1], h2 = hv[2], h3 = hv[3];
            float a0 = w0.x * h0.x, a1 = w2.x * h2.x;
            a0 = fmaf(w0.y, h0.y, a0); a1 = fmaf(w2.y, h2.y, a1);
            a0 = fmaf(w0.z, h0.z, a0); a1 = fmaf(w2.z, h2.z, a1);
            a0 = fmaf(w0.w, h0.w, a0); a1 = fmaf(w2.w, h2.w, a1);
            a0 = fmaf(w1.x, h1.x, a0); a1 = fmaf(w3.x, h3.x, a1);
            a0 = fmaf(w1.y, h1.y, a0); a1 = fmaf(w3.y, h3.y, a1);
            a0 = fmaf(w1.z, h1.z, a0); a1 = fmaf(w3.z, h3.z, a1);
            a0 = fmaf(w1.w, h1.w, a0); a1 = fmaf(w3.w, h3.w, a1);
            float acc = a0 + a1;
            acc += __shfl_xor(acc, 1);
            acc += __shfl_xor(acc, 2);
            acc += __shfl_xor(acc, 4);
            if (sub == 0) {
                acc += sbhead[oo];
                if (oo < 8) {
                    float rate = fmaf(2.99f, sigf(acc), 0.01f);
                    sRates[r][oo] = rate;
                    out[OFF_R + ((size_t)(b0 + r) * KSTEPS + k) * 8 + oo] = rate;
                } else {
                    float dh = 3.0f * sigf(acc);
                    sDhid[r][oo - 8] = dh;
                    out[OFF_D + ((size_t)(b0 + r) * KSTEPS + k) * 5 + (oo - 8)] = dh;
                }
            }
        }
        __syncthreads();

        // ---------- phase E: gh(k+1) partials (all) || u commit || RK4 (lanes 0,1) ----------
        {
            float g0 = bhhv, g1 = 0.0f;
            const h2v* h0p = (const h2v*)&sH2[0][hf * 64];
            const h2v* h1p = (const h2v*)&sH2[1][hf * 64];
#pragma unroll
            for (int i = 0; i < 32; i++) {
                g0 = fdot2(whh2[i], h0p[i], g0);
                g1 = fdot2(whh2[i], h1p[i], g1);
            }
            sGhP[hf][0][o] = g0;
            sGhP[hf][1][o] = g1;
        }
        if (t >= 256 && t < 260 && (k + 1) < KSTEPS) {
            if (t < 258) {
                int r = t - 256;
                *(float4*)&sU[(k + 1) & 1][r][0] = upf;
            } else {
                sDt[(k + 1) & 1][t - 258] = dpf;
            }
        }
        if (t < 2) {
            const int r = t;
            float ya[5];
            float kf1 = sRates[r][0], kf2 = sRates[r][1], kf3 = sRates[r][2], kf4 = sRates[r][3];
            float kr1 = sRates[r][4], kr2 = sRates[r][5], kr3 = sRates[r][6], kr4 = sRates[r][7];
            float um0 = sU[k & 1][r][0], um1 = sU[k & 1][r][1];
            float um2 = sU[k & 1][r][2], um3 = sU[k & 1][r][3];
#pragma unroll
            for (int s = 0; s < 5; s++) {
                float jmp = um0 * sU2Y[s];
                jmp = fmaf(um1, sU2Y[5 + s], jmp);
                jmp = fmaf(um2, sU2Y[10 + s], jmp);
                jmp = fmaf(um3, sU2Y[15 + s], jmp);
                ya[s] = sY[r][s] + jmp + sDhid[r][s];
            }
            const float hs = sDt[k & 1][r] * 0.1f;     // dt / N_SUB
            const float h2 = 0.5f * hs;
            const float h6 = hs * (1.0f / 6.0f);
            for (int ss = 0; ss < 10; ss++) {
                float k1[5], k2[5], k3[5], k4[5], tp[5];
                CHAIN_RHS(k1, ya);
#pragma unroll
                for (int i = 0; i < 5; i++) tp[i] = fmaf(h2, k1[i], ya[i]);
                CHAIN_RHS(k2, tp);
#pragma unroll
                for (int i = 0; i < 5; i++) tp[i] = fmaf(h2, k2[i], ya[i]);
                CHAIN_RHS(k3, tp);
#pragma unroll
                for (int i = 0; i < 5; i++) tp[i] = fmaf(hs, k3[i], ya[i]);
                CHAIN_RHS(k4, tp);
#pragma unroll
                for (int i = 0; i < 5; i++) {
                    float sum = k1[i] + 2.0f * (k2[i] + k3[i]) + k4[i];
                    ya[i] = fmaxf(fmaf(h6, sum, ya[i]), 0.0f);
                }
            }
#pragma unroll
            for (int i = 0; i < 5; i++) {
                sY[r][i] = ya[i];
                out[((size_t)(b0 + r) * KSTEPS + k) * 5 + i] = ya[i];
            }
        }
        __syncthreads();
    }
}

}  // namespace

extern "C" void kernel_launch(void* const* d_in, const int* in_sizes, int n_in,
                              void* d_out, int out_size, void* d_ws, size_t ws_size,
                              hipStream_t stream) {
    const float* y0     = (const float*)d_in[0];
    const float* u_seq  = (const float*)d_in[1];
    const float* dt_seq = (const float*)d_in[2];
    const float* W_lift = (const float*)d_in[3];
    const float* b_lift = (const float*)d_in[4];
    const float* W_ih   = (const float*)d_in[5];
    const float* W_hh   = (const float*)d_in[6];
    const float* b_ih   = (const float*)d_in[7];
    const float* b_hh   = (const float*)d_in[8];
    const float* W_head = (const float*)d_in[9];
    const float* b_head = (const float*)d_in[10];
    const float* u2y    = (const float*)d_in[11];
    float* out = (float*)d_out;

    rnn_v10<<<256, 768, 0, stream>>>(y0, u_seq, dt_seq, W_lift, b_lift,
                                     W_ih, W_hh, b_ih, b_hh, W_head, b_head,
                                     u2y, out);
}

// Round 11
// 3177.658 us; speedup vs baseline: 1.2786x; 1.2786x over previous
//
#include <hip/hip_runtime.h>

namespace {

typedef _Float16 __attribute__((ext_vector_type(2))) h2v;   // one VGPR = 2 f16

constexpr int KST = 1024;
constexpr size_t OFF_R = (size_t)512 * KST * 5;
constexpr size_t OFF_D = OFF_R + (size_t)512 * KST * 8;

__device__ __forceinline__ float sigf(float x) { return 1.0f / (1.0f + __expf(-x)); }
__device__ __forceinline__ float tanhfast(float x) {
    float e2 = __expf(2.0f * x);
    return 1.0f - 2.0f / (e2 + 1.0f);
}
__device__ __forceinline__ float fdot2(h2v a, h2v b, float c) {
    return __builtin_amdgcn_fdot2(a, b, c, false);
}
// DPP lane shifts within 16-lane rows (0-fill at edges). State-per-lane RK4:
// lane i of each 16-lane group holds state i; rows 0/1 at lanes 0-4 / 16-20,
// so the 16-lane DPP row boundary isolates the two batch rows.
__device__ __forceinline__ float dpp_shr1(float v) {   // lane i <- lane i-1
    return __builtin_bit_cast(float, __builtin_amdgcn_update_dpp(
        0, __builtin_bit_cast(int, v), 0x111, 0xf, 0xf, true));
}
__device__ __forceinline__ float dpp_shl1(float v) {   // lane i <- lane i+1
    return __builtin_bit_cast(float, __builtin_amdgcn_update_dpp(
        0, __builtin_bit_cast(int, v), 0x101, 0xf, 0xf, true));
}

// Register-budget law (r1-r6): budget = 256 / ceil(waves_per_WG/4) -> 84 VGPRs
// for 768-thread WGs. f16-packed hi weights (48 regs) fit; W_ih residuals in
// LDS (3rd fdot2 term) keep all gate errors <=1e-4, 100x under the ~0.01-0.05
// trajectory-flip threshold (r3 passed at 0.01; v9 failed at ~0.02-0.3).
// v8's 3-barrier schedule + DPP-RK4 proven mathematically correct (failed only
// on v7's thin numerics margin) -> this is v8 schedule x v10 numerics.
__global__ __launch_bounds__(768, 3) void rnn_v11(
    const float* __restrict__ y0,     const float* __restrict__ u_seq,
    const float* __restrict__ dt_seq, const float* __restrict__ W_lift,
    const float* __restrict__ b_lift, const float* __restrict__ W_ih,
    const float* __restrict__ W_hh,   const float* __restrict__ b_ih,
    const float* __restrict__ b_hh,   const float* __restrict__ W_head,
    const float* __restrict__ b_head, const float* __restrict__ u2y,
    float* __restrict__ out)
{
    const int t    = threadIdx.x;        // 0..767
    const int lane = t & 63;
    const int wid  = t >> 6;
    const int hf   = (t >= 384) ? 1 : 0; // column half (wave-uniform)
    const int o    = t - hf * 384;       // owned GRU output row 0..383
    const int b0   = blockIdx.x * 2;     // two batch rows per WG

    __shared__ alignas(16) float sWlift[64 * 9];
    __shared__ float sblift[64];
    __shared__ alignas(16) float sWheadP[13 * 132];      // padded stride 132
    __shared__ float sbhead[16];
    __shared__ float sU2Y[20];                           // u2y row-major (U,P)
    __shared__ alignas(16) _Float16 sX2hi[2][64];        // x high f16
    __shared__ alignas(16) _Float16 sX2lo[2][64];        // x residual f16
    __shared__ alignas(16) _Float16 sWihLo[2][384][36];  // W_ih f16 residuals (72B stride)
    __shared__ alignas(16) float sH[2][128];             // h fp32 (head consumer)
    __shared__ alignas(16) _Float16 sH2[2][128];         // h f16 (gh consumer)
    __shared__ alignas(16) float sGiP[2][2][384];        // [half][row][out]
    __shared__ alignas(16) float sGhP[2][2][384];
    __shared__ float sY[2][8];

    // ---- f16-packed per-thread hi weight rows (48 VGPRs) ----
    h2v wih2[16];   // W_ih[o][hf*32 .. +31] (hi)
    h2v whh2[32];   // W_hh[o][hf*64 .. +63] (hi)
    {
        const float* p = W_ih + (size_t)o * 64 + hf * 32;
#pragma unroll
        for (int i = 0; i < 16; i++)
            wih2[i] = h2v{(_Float16)p[2 * i], (_Float16)p[2 * i + 1]};
        const float* q = W_hh + (size_t)o * 128 + hf * 64;
#pragma unroll
        for (int i = 0; i < 32; i++)
            whh2[i] = h2v{(_Float16)q[2 * i], (_Float16)q[2 * i + 1]};
    }
    const float bihv = hf ? 0.0f : b_ih[o];
    const float bhhv = hf ? 0.0f : b_hh[o];
#pragma unroll
    for (int i = 0; i < 16; i++) asm volatile("" : "+v"(wih2[i]));
#pragma unroll
    for (int i = 0; i < 32; i++) asm volatile("" : "+v"(whh2[i]));

    // ---- cooperative LDS init ----
    for (int i = t; i < 576; i += 768) sWlift[i] = W_lift[i];
    if (t < 64) sblift[t] = b_lift[t];
    for (int i = t; i < 13 * 128; i += 768) {
        int oo = i >> 7, c = i & 127;
        sWheadP[oo * 132 + c] = W_head[i];
    }
    for (int i = t; i < 2 * 384 * 32; i += 768) {   // W_ih residuals
        int hh = i / (384 * 32);
        int rem = i - hh * 384 * 32;
        int oo = rem >> 5, c = rem & 31;
        float w = W_ih[(size_t)oo * 64 + hh * 32 + c];
        _Float16 wh = (_Float16)w;
        sWihLo[hh][oo][c] = (_Float16)(w - (float)wh);
    }
    if (t < 13) sbhead[t] = b_head[t];
    if (t < 20) sU2Y[t] = u2y[t];
    if (t < 256) {
        sH[t >> 7][t & 127] = 0.0f;
        sH2[t >> 7][t & 127] = (_Float16)0.0f;
    }
    if (t < 10) { int r = t / 5, s = t % 5; sY[r][s] = y0[(b0 + r) * 5 + s] + 0.01f; }
    sGhP[hf][0][o] = bhhv;   // gh(0) = b_hh (h0 = 0)
    sGhP[hf][1][o] = bhhv;
    __syncthreads();

    auto do_gi = [&]() {   // gi = Whi*xhi + Whi*xlo + Wlo*xhi  (exact v10 order)
        float g0 = bihv, g1 = 0.0f;
        const h2v* xh0 = (const h2v*)&sX2hi[0][hf * 32];
        const h2v* xh1 = (const h2v*)&sX2hi[1][hf * 32];
        const h2v* xl0 = (const h2v*)&sX2lo[0][hf * 32];
        const h2v* xl1 = (const h2v*)&sX2lo[1][hf * 32];
        const h2v* wlo = (const h2v*)&sWihLo[hf][o][0];
#pragma unroll
        for (int i = 0; i < 16; i++) {
            h2v wl = wlo[i];
            g0 = fdot2(wih2[i], xh0[i], g0);
            g0 = fdot2(wih2[i], xl0[i], g0);
            g0 = fdot2(wl, xh0[i], g0);
            g1 = fdot2(wih2[i], xh1[i], g1);
            g1 = fdot2(wih2[i], xl1[i], g1);
            g1 = fdot2(wl, xh1[i], g1);
        }
        sGiP[hf][0][o] = g0;
        sGiP[hf][1][o] = g1;
    };
    auto do_gh = [&]() {
        float g0 = bhhv, g1 = 0.0f;
        const h2v* h0p = (const h2v*)&sH2[0][hf * 64];
        const h2v* h1p = (const h2v*)&sH2[1][hf * 64];
#pragma unroll
        for (int i = 0; i < 32; i++) {
            g0 = fdot2(whh2[i], h0p[i], g0);
            g1 = fdot2(whh2[i], h1p[i], g1);
        }
        sGhP[hf][0][o] = g0;
        sGhP[hf][1][o] = g1;
    };
    auto do_lift = [&](float4 u0, float4 u1) {   // wave 0; lane = x-output index
        const float* wl = &sWlift[lane * 9];
        float bl = sblift[lane];
        float a0 = bl, a1 = bl;
        a0 = fmaf(wl[0], u0.x, a0);      a1 = fmaf(wl[0], u1.x, a1);
        a0 = fmaf(wl[1], u0.y, a0);      a1 = fmaf(wl[1], u1.y, a1);
        a0 = fmaf(wl[2], u0.z, a0);      a1 = fmaf(wl[2], u1.z, a1);
        a0 = fmaf(wl[3], u0.w, a0);      a1 = fmaf(wl[3], u1.w, a1);
        a0 = fmaf(wl[4], sY[0][0], a0);  a1 = fmaf(wl[4], sY[1][0], a1);
        a0 = fmaf(wl[5], sY[0][1], a0);  a1 = fmaf(wl[5], sY[1][1], a1);
        a0 = fmaf(wl[6], sY[0][2], a0);  a1 = fmaf(wl[6], sY[1][2], a1);
        a0 = fmaf(wl[7], sY[0][3], a0);  a1 = fmaf(wl[7], sY[1][3], a1);
        a0 = fmaf(wl[8], sY[0][4], a0);  a1 = fmaf(wl[8], sY[1][4], a1);
        float x0 = a0 * sigf(a0), x1 = a1 * sigf(a1);   // silu fp32
        _Float16 xh0 = (_Float16)x0;
        sX2hi[0][lane] = xh0;
        sX2lo[0][lane] = (_Float16)(x0 - (float)xh0);
        _Float16 xh1 = (_Float16)x1;
        sX2hi[1][lane] = xh1;
        sX2lo[1][lane] = (_Float16)(x1 - (float)xh1);
    };

    // ---- prologue: lift(0), gi(0) ----
    if (wid == 0) {
        float4 u0 = *(const float4*)&u_seq[((size_t)b0 * KST) * 4];
        float4 u1 = *(const float4*)&u_seq[((size_t)(b0 + 1) * KST) * 4];
        do_lift(u0, u1);
    }
    __syncthreads();
    do_gi();
    __syncthreads();

    for (int k = 0; k < KST; k++) {
        // ---------- Ψ1: gates(k) ----------
        if (t < 256) {
            int r = t >> 7, q = t & 127;
            float ir  = sGiP[0][r][q]       + sGiP[1][r][q];
            float iz  = sGiP[0][r][q + 128] + sGiP[1][r][q + 128];
            float in_ = sGiP[0][r][q + 256] + sGiP[1][r][q + 256];
            float hr  = sGhP[0][r][q]       + sGhP[1][r][q];
            float hz  = sGhP[0][r][q + 128] + sGhP[1][r][q + 128];
            float hn  = sGhP[0][r][q + 256] + sGhP[1][r][q + 256];
            float rr = sigf(ir + hr);
            float z  = sigf(iz + hz);
            float n  = tanhfast(fmaf(rr, hn, in_));
            float h  = sH[r][q];
            float hnew = fmaf(z, h - n, n);
            sH[r][q] = hnew;
            sH2[r][q] = (_Float16)hnew;
        }
        __syncthreads();

        // ---------- Ψ2: gh(k+1) all waves; wave 0 also head -> RK4 -> lift ----------
        float4 ukr{}, un0{}, un1{};
        float dtr = 0.0f;
        const int rh = (lane >> 4) & 1;
        if (wid == 0) {   // early global loads (L2-resident); latency hides under gh
            int kn = (k + 1 < KST) ? k + 1 : KST - 1;
            ukr = *(const float4*)&u_seq[((size_t)(b0 + rh) * KST + k) * 4];
            dtr = dt_seq[(size_t)(b0 + rh) * KST + k];
            un0 = *(const float4*)&u_seq[((size_t)b0 * KST + kn) * 4];
            un1 = *(const float4*)&u_seq[((size_t)(b0 + 1) * KST + kn) * 4];
        }
        do_gh();
        if (wid == 0) {
            // ----- head: lane = hh*32 + rh*16 + oo; exact v10 summation tree -----
            const int hh = (lane >> 5) & 1;
            const int oo = lane & 15;
            float accv[4] = {0.f, 0.f, 0.f, 0.f};
            if (oo < 13) {
                const float4* wv = (const float4*)&sWheadP[oo * 132 + hh * 64];
                const float4* hv = (const float4*)&sH[rh][hh * 64];
#pragma unroll
                for (int c = 0; c < 4; c++) {
                    float4 w0 = wv[4 * c], w1 = wv[4 * c + 1], w2 = wv[4 * c + 2], w3 = wv[4 * c + 3];
                    float4 h0 = hv[4 * c], h1 = hv[4 * c + 1], h2 = hv[4 * c + 2], h3 = hv[4 * c + 3];
                    float a0 = w0.x * h0.x, a1 = w2.x * h2.x;
                    a0 = fmaf(w0.y, h0.y, a0); a1 = fmaf(w2.y, h2.y, a1);
                    a0 = fmaf(w0.z, h0.z, a0); a1 = fmaf(w2.z, h2.z, a1);
                    a0 = fmaf(w0.w, h0.w, a0); a1 = fmaf(w2.w, h2.w, a1);
                    a0 = fmaf(w1.x, h1.x, a0); a1 = fmaf(w3.x, h3.x, a1);
                    a0 = fmaf(w1.y, h1.y, a0); a1 = fmaf(w3.y, h3.y, a1);
                    a0 = fmaf(w1.z, h1.z, a0); a1 = fmaf(w3.z, h3.z, a1);
                    a0 = fmaf(w1.w, h1.w, a0); a1 = fmaf(w3.w, h3.w, a1);
                    accv[c] = a0 + a1;
                }
            }
            float p1 = accv[0] + accv[1];
            float p2 = accv[2] + accv[3];
            float part = p1 + p2;                       // ((s0+s1)+(s2+s3))
            float tot = part + __shfl_xor(part, 32);    // + ((s4+s5)+(s6+s7))
            float gval = 0.0f;
            if (oo < 13 && hh == 0) {
                float raw = tot + sbhead[oo];
                if (oo < 8) {
                    gval = fmaf(2.99f, sigf(raw), 0.01f);
                    out[OFF_R + ((size_t)(b0 + rh) * KST + k) * 8 + oo] = gval;
                } else {
                    gval = 3.0f * sigf(raw);
                    out[OFF_D + ((size_t)(b0 + rh) * KST + k) * 5 + (oo - 8)] = gval;
                }
            }

            // ----- RK4, state-per-lane (bit-equivalent to serial flux form) -----
            const int i = lane & 15;
            const int base = rh * 16;
            float kf = __shfl(gval, base + i - 1);
            float kr = __shfl(gval, base + i + 3);
            if (!(i >= 1 && i <= 4)) { kf = 0.0f; kr = 0.0f; }
            float dh = __shfl(gval, base + 8 + i);
            const int ii = (i < 5) ? i : 0;
            float yp = sY[rh][ii];
            float jmp = ukr.x * sU2Y[ii];
            jmp = fmaf(ukr.y, sU2Y[5 + ii], jmp);
            jmp = fmaf(ukr.z, sU2Y[10 + ii], jmp);
            jmp = fmaf(ukr.w, sU2Y[15 + ii], jmp);
            float ya = yp + jmp + dh;
            const float hs = dtr * 0.1f;
            const float h2s = 0.5f * hs;
            const float h6 = hs * (1.0f / 6.0f);
#pragma unroll
            for (int ss = 0; ss < 10; ss++) {
                float yv = dpp_shr1(ya);
                float f1 = kf * yv - kr * ya;
                float k1 = f1 - dpp_shl1(f1);
                float tp = fmaf(h2s, k1, ya);
                yv = dpp_shr1(tp);
                float f2 = kf * yv - kr * tp;
                float k2 = f2 - dpp_shl1(f2);
                tp = fmaf(h2s, k2, ya);
                yv = dpp_shr1(tp);
                float f3 = kf * yv - kr * tp;
                float k3 = f3 - dpp_shl1(f3);
                tp = fmaf(hs, k3, ya);
                yv = dpp_shr1(tp);
                float f4 = kf * yv - kr * tp;
                float k4 = f4 - dpp_shl1(f4);
                float sum = k1 + 2.0f * (k2 + k3) + k4;
                ya = fmaxf(fmaf(h6, sum, ya), 0.0f);
            }
            if (lane < 32 && i < 5) {
                sY[rh][i] = ya;
                out[((size_t)(b0 + rh) * KST + k) * 5 + i] = ya;
            }
            asm volatile("s_waitcnt lgkmcnt(0)" ::: "memory");   // sY writes visible wave-wide
            do_lift(un0, un1);                                   // lift(k+1)
        }
        __syncthreads();

        // ---------- Ψ3: gi(k+1) ----------
        do_gi();
        __syncthreads();
    }
}

}  // namespace

extern "C" void kernel_launch(void* const* d_in, const int* in_sizes, int n_in,
                              void* d_out, int out_size, void* d_ws, size_t ws_size,
                              hipStream_t stream) {
    const float* y0     = (const float*)d_in[0];
    const float* u_seq  = (const float*)d_in[1];
    const float* dt_seq = (const float*)d_in[2];
    const float* W_lift = (const float*)d_in[3];
    const float* b_lift = (const float*)d_in[4];
    const float* W_ih   = (const float*)d_in[5];
    const float* W_hh   = (const float*)d_in[6];
    const float* b_ih   = (const float*)d_in[7];
    const float* b_hh   = (const float*)d_in[8];
    const float* W_head = (const float*)d_in[9];
    const float* b_head = (const float*)d_in[10];
    const float* u2y    = (const float*)d_in[11];
    float* out = (float*)d_out;

    rnn_v11<<<256, 768, 0, stream>>>(y0, u_seq, dt_seq, W_lift, b_lift,
                                     W_ih, W_hh, b_ih, b_hh, W_head, b_head,
                                     u2y, out);
}